// Round 12
// baseline (79.860 us; speedup 1.0000x reference)
//
#include <hip/hip_runtime.h>
#include <hip/hip_bf16.h>

#define N 4096
#define DMODEL 128
#define H 4
#define DK 32
#define NSPLIT 16
// q is pre-scaled by (1/sqrt(32)) * log2(e) so all exponentials are raw v_exp_f32 (2^x)
#define QSCALE ((float)(0.17677669529663687 * 1.4426950408889634))

#if __has_builtin(__builtin_amdgcn_exp2f)
#define EXP2(x) __builtin_amdgcn_exp2f(x)
#else
#define EXP2(x) exp2f(x)
#endif

typedef __bf16 bf16x8 __attribute__((ext_vector_type(8)));
typedef __bf16 bf16x4 __attribute__((ext_vector_type(4)));
typedef float f32x4 __attribute__((ext_vector_type(4)));

// ---------------- projections: q~ = (x^T Qw + Qb)*QSCALE, k = x^T Kw + Kb; also x -> bf16 ----
// grid 256 blocks x 256 threads; block owns 16 n-columns (R5-proven shape).
__global__ __launch_bounds__(256, 4)
void proj_kernel(const float* __restrict__ x,
                 const float* __restrict__ Qw, const float* __restrict__ Qbias,
                 const float* __restrict__ Kw, const float* __restrict__ Kbias,
                 __bf16* __restrict__ qb, __bf16* __restrict__ kb, __bf16* __restrict__ xb) {
  __shared__ __align__(16) float xs[128 * 16];  // [d][16 n]
  const int tid = threadIdx.x;
  const int n0 = blockIdx.x * 16;
  #pragma unroll
  for (int it = 0; it < 2; ++it) {
    int idx = tid + it * 256;        // f32x4 index, 512 total
    int dd = idx >> 2, j4 = idx & 3;
    f32x4 v = *(const f32x4*)(x + (size_t)dd * N + n0 + j4 * 4);
    ((f32x4*)xs)[idx] = v;
    bf16x4 o;
    o[0] = (__bf16)v[0]; o[1] = (__bf16)v[1]; o[2] = (__bf16)v[2]; o[3] = (__bf16)v[3];
    *(bf16x4*)(xb + (size_t)dd * N + n0 + j4 * 4) = o;
  }
  __syncthreads();
  const int a = tid & 127;   // output feature 0..127
  const int g = tid >> 7;    // 0 = q, 1 = k
  const float* __restrict__ W = g ? Kw : Qw;
  float acc[16];
  #pragma unroll
  for (int j = 0; j < 16; ++j) acc[j] = 0.f;
  const f32x4* xs4 = (const f32x4*)xs;
  #pragma unroll 8
  for (int dd = 0; dd < 128; ++dd) {
    float w = W[dd * 128 + a];
    #pragma unroll
    for (int jj = 0; jj < 4; ++jj) {
      f32x4 xv = xs4[dd * 4 + jj];
      #pragma unroll
      for (int e = 0; e < 4; ++e) acc[jj * 4 + e] += xv[e] * w;
    }
  }
  const float bias = (g ? Kbias : Qbias)[a];
  const float sc = g ? 1.0f : QSCALE;
  __bf16* __restrict__ dst = g ? kb : qb;
  const int h = a >> 5, c = a & 31;
  #pragma unroll
  for (int j = 0; j < 16; ++j)
    dst[((size_t)h * N + n0 + j) * DK + c] = (__bf16)((acc[j] + bias) * sc);
}

// ---------------- pass 1: Zinv[h][n] = 0.25 / sum_m exp2(q~_n . k_m) ----------------
// (1/4 head-mean folded in: work-neutral in z, removes 16 v_mul/iter in attn.)
// grid: H * N/64 = 256 blocks x 1024 threads (16 waves); waves split m 16 ways. No swizzle.
__global__ __launch_bounds__(1024, 4)
void z_kernel(const __bf16* __restrict__ qb, const __bf16* __restrict__ kb,
              float* __restrict__ Zinv) {
  const int h = blockIdx.x >> 6;
  const int n0 = (blockIdx.x & 63) * 64;
  const int wave = threadIdx.x >> 6;
  const int l = threadIdx.x & 63;
  const int lr = l & 15;
  const int kc = (l >> 4) * 8;
  bf16x8 qf[4];
  #pragma unroll
  for (int t = 0; t < 4; ++t)
    qf[t] = *(const bf16x8*)(qb + ((size_t)h * N + n0 + t * 16 + lr) * DK + kc);
  float z[16];
  #pragma unroll
  for (int i = 0; i < 16; ++i) z[i] = 0.f;
  const int mstart = wave * (N / 16);
  #pragma unroll 2
  for (int m0 = mstart; m0 < mstart + N / 16; m0 += 16) {
    bf16x8 kf = *(const bf16x8*)(kb + ((size_t)h * N + m0 + lr) * DK + kc);
    #pragma unroll
    for (int t = 0; t < 4; ++t) {
      f32x4 s = __builtin_amdgcn_mfma_f32_16x16x32_bf16(qf[t], kf, (f32x4){0.f, 0.f, 0.f, 0.f}, 0, 0, 0);
      #pragma unroll
      for (int j = 0; j < 4; ++j) z[t * 4 + j] += EXP2(s[j]);
    }
  }
  #pragma unroll
  for (int off = 1; off < 16; off <<= 1)
    #pragma unroll
    for (int i = 0; i < 16; ++i) z[i] += __shfl_xor(z[i], off, 64);
  __shared__ float zred[16][64];
  if (lr == 0) {
    int g = l >> 4;
    #pragma unroll
    for (int t = 0; t < 4; ++t)
      #pragma unroll
      for (int j = 0; j < 4; ++j) zred[wave][t * 16 + g * 4 + j] = z[t * 4 + j];
  }
  __syncthreads();
  if (threadIdx.x < 64) {
    int row = threadIdx.x;
    float s = 0.f;
    #pragma unroll
    for (int w = 0; w < 16; ++w) s += zred[w][row];
    Zinv[(size_t)h * N + n0 + row] = 0.25f / s;
  }
}

// ---------------- pass 2: out partial = x @ P_mean for a 64-col m tile, 1/NSPLIT of n ----
// R5 structure verbatim; NSPLIT 16 -> grid 1024 = 4 blocks/CU (16 waves/CU), q/x traffic
// unchanged (thin-n, not thin-m). launch_bounds(256,4) so occupancy isn't bound-capped.
__global__ __launch_bounds__(256, 4)
void attn_out_kernel(const __bf16* __restrict__ qb, const __bf16* __restrict__ kb,
                     const __bf16* __restrict__ xb, const float* __restrict__ Zinv,
                     float* __restrict__ partial) {
  const int mt = blockIdx.x & 63;
  const int sp = blockIdx.x >> 6;
  const int m0 = mt * 64;
  const int nstart = sp * (N / NSPLIT);
  const int nend = nstart + N / NSPLIT;
  const int wid = threadIdx.x >> 6;
  const int l = threadIdx.x & 63;
  const int lr = l & 15;
  const int lg = l >> 4;
  const int kc = lg * 8;

  __shared__ __align__(16) __bf16 PT[64][72];  // [m][n], +8 pad
  __shared__ float zl[H][64];

  bf16x8 kf[H][4];
  #pragma unroll
  for (int h = 0; h < H; ++h)
    #pragma unroll
    for (int t = 0; t < 4; ++t)
      kf[h][t] = *(const bf16x8*)(kb + ((size_t)h * N + m0 + t * 16 + lr) * DK + kc);

  f32x4 acc[2][4];
  #pragma unroll
  for (int dt = 0; dt < 2; ++dt)
    #pragma unroll
    for (int t = 0; t < 4; ++t) acc[dt][t] = (f32x4){0.f, 0.f, 0.f, 0.f};

  // prologue prefetch (iteration 0)
  float zv = Zinv[(size_t)wid * N + nstart + l];
  bf16x8 qf[H];
  #pragma unroll
  for (int h = 0; h < H; ++h)
    qf[h] = *(const bf16x8*)(qb + ((size_t)h * N + nstart + wid * 16 + lr) * DK + kc);

  for (int n0 = nstart; n0 < nend; n0 += 64) {
    zl[wid][l] = zv;               // zl readers of prev iter finished before prev sync2
    __syncthreads();               // sync1: zl visible; PT free (prev PV readers done)

    // issue next-iteration prefetch early so it overlaps the S-phase compute
    const int n1 = (n0 + 64 < nend) ? n0 + 64 : nstart;
    float zv_n = Zinv[(size_t)wid * N + n1 + l];
    bf16x8 qf_n[H];
    #pragma unroll
    for (int h = 0; h < H; ++h)
      qf_n[h] = *(const bf16x8*)(qb + ((size_t)h * N + n1 + wid * 16 + lr) * DK + kc);

    // ---- S phase: this wave's 16 n rows, all 4 heads summed in registers ----
    float psum[4][4];
    #pragma unroll
    for (int t = 0; t < 4; ++t)
      #pragma unroll
      for (int j = 0; j < 4; ++j) psum[t][j] = 0.f;

    #pragma unroll
    for (int h = 0; h < H; ++h) {
      float zi[4];
      #pragma unroll
      for (int j = 0; j < 4; ++j) zi[j] = zl[h][wid * 16 + lg * 4 + j];
      #pragma unroll
      for (int t = 0; t < 4; ++t) {
        f32x4 s = __builtin_amdgcn_mfma_f32_16x16x32_bf16(qf[h], kf[h][t],
                                                          (f32x4){0.f, 0.f, 0.f, 0.f}, 0, 0, 0);
        #pragma unroll
        for (int j = 0; j < 4; ++j)
          psum[t][j] += EXP2(s[j]) * zi[j];   // zi includes the 1/4 head-mean
      }
    }
    // packed b64 PT writes (cols wid*16+lg*4 .. +3 are contiguous)
    #pragma unroll
    for (int t = 0; t < 4; ++t) {
      bf16x4 pw;
      #pragma unroll
      for (int j = 0; j < 4; ++j) pw[j] = (__bf16)psum[t][j];
      *(bf16x4*)(&PT[t * 16 + lr][wid * 16 + lg * 4]) = pw;
    }

    // xa loads don't touch LDS: issue before the barrier to overlap it
    bf16x8 xa[2][2];
    #pragma unroll
    for (int kb2 = 0; kb2 < 2; ++kb2)
      #pragma unroll
      for (int dt = 0; dt < 2; ++dt)
        xa[kb2][dt] = *(const bf16x8*)(xb + (size_t)(wid * 32 + dt * 16 + lr) * N + n0 + kb2 * 32 + kc);
    __syncthreads();               // sync2: PT visible to PV readers

    // ---- PV phase ----
    #pragma unroll
    for (int kb2 = 0; kb2 < 2; ++kb2) {
      #pragma unroll
      for (int t = 0; t < 4; ++t) {
        bf16x8 pf = *(const bf16x8*)(&PT[t * 16 + lr][kb2 * 32 + kc]);
        #pragma unroll
        for (int dt = 0; dt < 2; ++dt)
          acc[dt][t] = __builtin_amdgcn_mfma_f32_16x16x32_bf16(xa[kb2][dt], pf, acc[dt][t], 0, 0, 0);
      }
    }
    zv = zv_n;
    #pragma unroll
    for (int h = 0; h < H; ++h) qf[h] = qf_n[h];
  }

  #pragma unroll
  for (int dt = 0; dt < 2; ++dt)
    #pragma unroll
    for (int t = 0; t < 4; ++t)
      #pragma unroll
      for (int j = 0; j < 4; ++j)
        partial[((size_t)sp * DMODEL + wid * 32 + dt * 16 + lg * 4 + j) * N + m0 + t * 16 + lr] =
            acc[dt][t][j];
}

// ---------------- reduce the NSPLIT partials ----------------
__global__ __launch_bounds__(256, 4)
void reduce_kernel(const float* __restrict__ partial, float* __restrict__ out) {
  int i = blockIdx.x * 256 + threadIdx.x;
  const f32x4* p = (const f32x4*)partial;
  f32x4 s = p[i];
  #pragma unroll
  for (int sp = 1; sp < NSPLIT; ++sp) s += p[(size_t)sp * (DMODEL * N / 4) + i];
  ((f32x4*)out)[i] = s;
}

extern "C" void kernel_launch(void* const* d_in, const int* in_sizes, int n_in,
                              void* d_out, int out_size, void* d_ws, size_t ws_size,
                              hipStream_t stream) {
  (void)in_sizes; (void)n_in; (void)out_size; (void)ws_size;
  const float* x  = (const float*)d_in[0];
  const float* Qw = (const float*)d_in[1];
  const float* Qb = (const float*)d_in[2];
  const float* Kw = (const float*)d_in[3];
  const float* Kb = (const float*)d_in[4];

  char* ws = (char*)d_ws;
  __bf16* qb   = (__bf16*)(ws);                          // 1 MB
  __bf16* kb   = (__bf16*)(ws + (1 << 20));              // 1 MB
  __bf16* xb   = (__bf16*)(ws + (2 << 20));              // 1 MB
  float*  Zinv = (float*)(ws + (3 << 20));               // 64 KB
  float*  part = (float*)(ws + (3 << 20) + (1 << 16));   // 32 MB (ws is 256 MiB per poison size)
  float*  out  = (float*)d_out;

  proj_kernel<<<dim3(N / 16), dim3(256), 0, stream>>>(x, Qw, Qb, Kw, Kb, qb, kb, xb);
  z_kernel<<<dim3(H * (N / 64)), dim3(1024), 0, stream>>>(qb, kb, Zinv);
  attn_out_kernel<<<dim3(64 * NSPLIT), dim3(256), 0, stream>>>(qb, kb, xb, Zinv, part);
  reduce_kernel<<<dim3(DMODEL * N / (4 * 256)), dim3(256), 0, stream>>>(part, out);
}

// Round 13
// 52.628 us; speedup vs baseline: 1.5174x; 1.5174x over previous
//
#include <hip/hip_runtime.h>
#include <hip/hip_bf16.h>

#define N 4096
#define DMODEL 128
#define H 4
#define DK 32
#define NSPLIT 8
// q is pre-scaled by (1/sqrt(32)) * log2(e) so all exponentials are raw v_exp_f32 (2^x)
#define QSCALE ((float)(0.17677669529663687 * 1.4426950408889634))

#if __has_builtin(__builtin_amdgcn_exp2f)
#define EXP2(x) __builtin_amdgcn_exp2f(x)
#else
#define EXP2(x) exp2f(x)
#endif

typedef __bf16 bf16x8 __attribute__((ext_vector_type(8)));
typedef __bf16 bf16x4 __attribute__((ext_vector_type(4)));
typedef float f32x4 __attribute__((ext_vector_type(4)));

// ---------------- projections: q~ = (x^T Qw + Qb)*QSCALE, k = x^T Kw + Kb; also x -> bf16 ----
// grid 256 blocks x 256 threads; block owns 16 n-columns (R5-proven shape).
__global__ __launch_bounds__(256, 4)
void proj_kernel(const float* __restrict__ x,
                 const float* __restrict__ Qw, const float* __restrict__ Qbias,
                 const float* __restrict__ Kw, const float* __restrict__ Kbias,
                 __bf16* __restrict__ qb, __bf16* __restrict__ kb, __bf16* __restrict__ xb) {
  __shared__ __align__(16) float xs[128 * 16];  // [d][16 n]
  const int tid = threadIdx.x;
  const int n0 = blockIdx.x * 16;
  #pragma unroll
  for (int it = 0; it < 2; ++it) {
    int idx = tid + it * 256;        // f32x4 index, 512 total
    int dd = idx >> 2, j4 = idx & 3;
    f32x4 v = *(const f32x4*)(x + (size_t)dd * N + n0 + j4 * 4);
    ((f32x4*)xs)[idx] = v;
    bf16x4 o;
    o[0] = (__bf16)v[0]; o[1] = (__bf16)v[1]; o[2] = (__bf16)v[2]; o[3] = (__bf16)v[3];
    *(bf16x4*)(xb + (size_t)dd * N + n0 + j4 * 4) = o;
  }
  __syncthreads();
  const int a = tid & 127;   // output feature 0..127
  const int g = tid >> 7;    // 0 = q, 1 = k
  const float* __restrict__ W = g ? Kw : Qw;
  float acc[16];
  #pragma unroll
  for (int j = 0; j < 16; ++j) acc[j] = 0.f;
  const f32x4* xs4 = (const f32x4*)xs;
  #pragma unroll 8
  for (int dd = 0; dd < 128; ++dd) {
    float w = W[dd * 128 + a];
    #pragma unroll
    for (int jj = 0; jj < 4; ++jj) {
      f32x4 xv = xs4[dd * 4 + jj];
      #pragma unroll
      for (int e = 0; e < 4; ++e) acc[jj * 4 + e] += xv[e] * w;
    }
  }
  const float bias = (g ? Kbias : Qbias)[a];
  const float sc = g ? 1.0f : QSCALE;
  __bf16* __restrict__ dst = g ? kb : qb;
  const int h = a >> 5, c = a & 31;
  #pragma unroll
  for (int j = 0; j < 16; ++j)
    dst[((size_t)h * N + n0 + j) * DK + c] = (__bf16)((acc[j] + bias) * sc);
}

// ---------------- pass 1: Zinv[h][n] = 0.25 / sum_m exp2(q~_n . k_m) ----------------
// (1/4 head-mean folded in; attn multiplies by Zinv only.)
// grid: H * N/64 = 256 blocks x 512 threads (8 waves); waves split the m range 8 ways.
// (R5-proven shape.)
__global__ __launch_bounds__(512, 4)
void z_kernel(const __bf16* __restrict__ qb, const __bf16* __restrict__ kb,
              float* __restrict__ Zinv) {
  const int h = blockIdx.x >> 6;
  const int n0 = (blockIdx.x & 63) * 64;
  const int wave = threadIdx.x >> 6;
  const int l = threadIdx.x & 63;
  const int lr = l & 15;
  const int kc = (l >> 4) * 8;
  bf16x8 qf[4];
  #pragma unroll
  for (int t = 0; t < 4; ++t)
    qf[t] = *(const bf16x8*)(qb + ((size_t)h * N + n0 + t * 16 + lr) * DK + kc);
  float z[16];
  #pragma unroll
  for (int i = 0; i < 16; ++i) z[i] = 0.f;
  const int mstart = wave * (N / 8);
  #pragma unroll 4
  for (int m0 = mstart; m0 < mstart + N / 8; m0 += 16) {
    bf16x8 kf = *(const bf16x8*)(kb + ((size_t)h * N + m0 + lr) * DK + kc);
    #pragma unroll
    for (int t = 0; t < 4; ++t) {
      f32x4 s = __builtin_amdgcn_mfma_f32_16x16x32_bf16(qf[t], kf, (f32x4){0.f, 0.f, 0.f, 0.f}, 0, 0, 0);
      #pragma unroll
      for (int j = 0; j < 4; ++j) z[t * 4 + j] += EXP2(s[j]);
    }
  }
  #pragma unroll
  for (int off = 1; off < 16; off <<= 1)
    #pragma unroll
    for (int i = 0; i < 16; ++i) z[i] += __shfl_xor(z[i], off, 64);
  __shared__ float zred[8][64];
  if (lr == 0) {
    int g = l >> 4;
    #pragma unroll
    for (int t = 0; t < 4; ++t)
      #pragma unroll
      for (int j = 0; j < 4; ++j) zred[wave][t * 16 + g * 4 + j] = z[t * 4 + j];
  }
  __syncthreads();
  if (threadIdx.x < 64) {
    int row = threadIdx.x;
    float s = 0.f;
    #pragma unroll
    for (int w = 0; w < 8; ++w) s += zred[w][row];
    Zinv[(size_t)h * N + n0 + row] = 0.25f / s;
  }
}

// ---------------- pass 2: out partial = x @ P_mean for a 64-col m tile, 1/NSPLIT of n ----
// R5 structure verbatim. Partial stores are NON-TEMPORAL (MUBUF nt): partial is written
// once and read once by reduce -- avoid write-allocate fetch + L2 pollution.
__global__ __launch_bounds__(256, 3)
void attn_out_kernel(const __bf16* __restrict__ qb, const __bf16* __restrict__ kb,
                     const __bf16* __restrict__ xb, const float* __restrict__ Zinv,
                     float* __restrict__ partial) {
  const int mt = blockIdx.x & 63;
  const int sp = blockIdx.x >> 6;
  const int m0 = mt * 64;
  const int nstart = sp * (N / NSPLIT);
  const int nend = nstart + N / NSPLIT;
  const int wid = threadIdx.x >> 6;
  const int l = threadIdx.x & 63;
  const int lr = l & 15;
  const int lg = l >> 4;
  const int kc = lg * 8;

  __shared__ __align__(16) __bf16 PT[64][72];  // [m][n], +8 pad
  __shared__ float zl[H][64];

  bf16x8 kf[H][4];
  #pragma unroll
  for (int h = 0; h < H; ++h)
    #pragma unroll
    for (int t = 0; t < 4; ++t)
      kf[h][t] = *(const bf16x8*)(kb + ((size_t)h * N + m0 + t * 16 + lr) * DK + kc);

  f32x4 acc[2][4];
  #pragma unroll
  for (int dt = 0; dt < 2; ++dt)
    #pragma unroll
    for (int t = 0; t < 4; ++t) acc[dt][t] = (f32x4){0.f, 0.f, 0.f, 0.f};

  // prologue prefetch (iteration 0)
  float zv = Zinv[(size_t)wid * N + nstart + l];
  bf16x8 qf[H];
  #pragma unroll
  for (int h = 0; h < H; ++h)
    qf[h] = *(const bf16x8*)(qb + ((size_t)h * N + nstart + wid * 16 + lr) * DK + kc);

  for (int n0 = nstart; n0 < nend; n0 += 64) {
    zl[wid][l] = zv;               // zl readers of prev iter finished before prev sync2
    __syncthreads();               // sync1: zl visible; PT free (prev PV readers done)

    // issue next-iteration prefetch early so it overlaps the S-phase compute
    const int n1 = (n0 + 64 < nend) ? n0 + 64 : nstart;
    float zv_n = Zinv[(size_t)wid * N + n1 + l];
    bf16x8 qf_n[H];
    #pragma unroll
    for (int h = 0; h < H; ++h)
      qf_n[h] = *(const bf16x8*)(qb + ((size_t)h * N + n1 + wid * 16 + lr) * DK + kc);

    // ---- S phase: this wave's 16 n rows, all 4 heads summed in registers ----
    float psum[4][4];
    #pragma unroll
    for (int t = 0; t < 4; ++t)
      #pragma unroll
      for (int j = 0; j < 4; ++j) psum[t][j] = 0.f;

    #pragma unroll
    for (int h = 0; h < H; ++h) {
      float zi[4];
      #pragma unroll
      for (int j = 0; j < 4; ++j) zi[j] = zl[h][wid * 16 + lg * 4 + j];
      #pragma unroll
      for (int t = 0; t < 4; ++t) {
        f32x4 s = __builtin_amdgcn_mfma_f32_16x16x32_bf16(qf[h], kf[h][t],
                                                          (f32x4){0.f, 0.f, 0.f, 0.f}, 0, 0, 0);
        #pragma unroll
        for (int j = 0; j < 4; ++j)
          psum[t][j] += EXP2(s[j]) * zi[j];   // zi includes the 1/4 head-mean
      }
    }
    // packed b64 PT writes (cols wid*16+lg*4 .. +3 are contiguous)
    #pragma unroll
    for (int t = 0; t < 4; ++t) {
      bf16x4 pw;
      #pragma unroll
      for (int j = 0; j < 4; ++j) pw[j] = (__bf16)psum[t][j];
      *(bf16x4*)(&PT[t * 16 + lr][wid * 16 + lg * 4]) = pw;
    }

    // xa loads don't touch LDS: issue before the barrier to overlap it
    bf16x8 xa[2][2];
    #pragma unroll
    for (int kb2 = 0; kb2 < 2; ++kb2)
      #pragma unroll
      for (int dt = 0; dt < 2; ++dt)
        xa[kb2][dt] = *(const bf16x8*)(xb + (size_t)(wid * 32 + dt * 16 + lr) * N + n0 + kb2 * 32 + kc);
    __syncthreads();               // sync2: PT visible to PV readers

    // ---- PV phase ----
    #pragma unroll
    for (int kb2 = 0; kb2 < 2; ++kb2) {
      #pragma unroll
      for (int t = 0; t < 4; ++t) {
        bf16x8 pf = *(const bf16x8*)(&PT[t * 16 + lr][kb2 * 32 + kc]);
        #pragma unroll
        for (int dt = 0; dt < 2; ++dt)
          acc[dt][t] = __builtin_amdgcn_mfma_f32_16x16x32_bf16(xa[kb2][dt], pf, acc[dt][t], 0, 0, 0);
      }
    }
    zv = zv_n;
    #pragma unroll
    for (int h = 0; h < H; ++h) qf[h] = qf_n[h];
  }

  // epilogue: non-temporal partial stores (written once, read once -- no write-allocate)
  #pragma unroll
  for (int dt = 0; dt < 2; ++dt)
    #pragma unroll
    for (int t = 0; t < 4; ++t)
      #pragma unroll
      for (int j = 0; j < 4; ++j)
        __builtin_nontemporal_store(
            acc[dt][t][j],
            &partial[((size_t)sp * DMODEL + wid * 32 + dt * 16 + lg * 4 + j) * N + m0 + t * 16 + lr]);
}

// ---------------- reduce the NSPLIT partials (non-temporal reads; read-once data) ------
__global__ __launch_bounds__(256, 4)
void reduce_kernel(const float* __restrict__ partial, float* __restrict__ out) {
  int i = blockIdx.x * 256 + threadIdx.x;
  const f32x4* p = (const f32x4*)partial;
  f32x4 s = __builtin_nontemporal_load(p + i);
  #pragma unroll
  for (int sp = 1; sp < NSPLIT; ++sp)
    s += __builtin_nontemporal_load(p + (size_t)sp * (DMODEL * N / 4) + i);
  ((f32x4*)out)[i] = s;
}

extern "C" void kernel_launch(void* const* d_in, const int* in_sizes, int n_in,
                              void* d_out, int out_size, void* d_ws, size_t ws_size,
                              hipStream_t stream) {
  (void)in_sizes; (void)n_in; (void)out_size; (void)ws_size;
  const float* x  = (const float*)d_in[0];
  const float* Qw = (const float*)d_in[1];
  const float* Qb = (const float*)d_in[2];
  const float* Kw = (const float*)d_in[3];
  const float* Kb = (const float*)d_in[4];

  char* ws = (char*)d_ws;
  __bf16* qb   = (__bf16*)(ws);                          // 1 MB
  __bf16* kb   = (__bf16*)(ws + (1 << 20));              // 1 MB
  __bf16* xb   = (__bf16*)(ws + (2 << 20));              // 1 MB
  float*  Zinv = (float*)(ws + (3 << 20));               // 64 KB
  float*  part = (float*)(ws + (3 << 20) + (1 << 16));   // 16 MB
  float*  out  = (float*)d_out;

  proj_kernel<<<dim3(N / 16), dim3(256), 0, stream>>>(x, Qw, Qb, Kw, Kb, qb, kb, xb);
  z_kernel<<<dim3(H * (N / 64)), dim3(512), 0, stream>>>(qb, kb, Zinv);
  attn_out_kernel<<<dim3(64 * NSPLIT), dim3(256), 0, stream>>>(qb, kb, xb, Zinv, part);
  reduce_kernel<<<dim3(DMODEL * N / (4 * 256)), dim3(256), 0, stream>>>(part, out);
}